// Round 4
// baseline (793.252 us; speedup 1.0000x reference)
//
#include <hip/hip_runtime.h>
#include <hip/hip_bf16.h>
#include <hip/hip_fp16.h>
#include <cstdint>

typedef __attribute__((ext_vector_type(8))) short short8;   // 8 bf16 = 4 VGPRs
typedef __attribute__((ext_vector_type(4))) float floatx4;  // 4 fp32 acc
typedef __attribute__((ext_vector_type(4))) int   intx4;    // for nontemporal ld

#define LEAKY_ALPHA 0.2f

__device__ __forceinline__ unsigned short f2bf_rne(float f) {
    unsigned u = __float_as_uint(f);
    unsigned r = u + 0x7FFFu + ((u >> 16) & 1u);   // round-to-nearest-even
    return (unsigned short)(r >> 16);
}

__device__ __forceinline__ unsigned pk2bf(float lo, float hi) {   // v_cvt_pk_bf16_f32
    union { __hip_bfloat162 b; unsigned u; } c;
    c.b = __float22bfloat162_rn(make_float2(lo, hi));
    return c.u;
}

__device__ __forceinline__ float2 h2f2(unsigned w) {
    union { unsigned u; __half2 h; } c; c.u = w;
    return __half22float2(c.h);
}

// Within-tile column permutation (shared by k_h hT order, e2s staging, ballot
// mask): storage slot nc' = 8w + j  <->  in-tile column 4j + w  (w=0..3,j=0..7)

// ---------------------------------------------------------------------------
// Kernel 1: h = inp @ W (fp32); e1=(exp(s1),exp(.2*s1)) fp32 per row,
// e2h=(exp(s2),exp(.2*s2)) half2 per col; hT bf16 TILED+PERMUTED:
// [b][tile=n/32][o(64)][nc'] with nc' = 8*(col%4) + col/4 within the tile.
// Round-4: 32-row tiles / 1024 blocks (4 blocks/CU, was 2) and 4-row-blocked
// inner loop (one W load feeds 4 rows -> 4x fewer L1 loads, ~40% less VALU).
// Per-row f-ascending accumulation order is IDENTICAL to the verified k_h,
// so results are bit-identical. (Round-3 cooperative fusion failed: coop
// launch silently no-ops under the harness's graph capture.)
// ---------------------------------------------------------------------------
__global__ __launch_bounds__(256) void k_h(const float* __restrict__ inp,
                                           const float* __restrict__ W,
                                           const float* __restrict__ a,
                                           unsigned short* __restrict__ hT,
                                           float2* __restrict__ e1,
                                           __half2* __restrict__ e2h) {
    __shared__ float hs[32][65];   // +1 pad
    const int tid  = threadIdx.x;
    const int wv   = tid >> 6;
    const int lane = tid & 63;
    const int blk  = blockIdx.x;
    const int b     = blk >> 7;          // 0..7
    const int tile  = blk & 127;         // 32-row tile index
    const int ibase = tile * 32;

    const float a1 = a[lane];
    const float a2 = a[64 + lane];

    // each wave: 8 rows, in two 4-row blocks
    #pragma unroll 1
    for (int rr = 0; rr < 8; rr += 4) {
        const int rloc = wv * 8 + rr;
        const int row  = ibase + rloc;
        const float* ip = inp + ((size_t)(b * 4096 + row)) * 128;  // wave-uniform
        float ac0 = 0.f, ac1 = 0.f, ac2 = 0.f, ac3 = 0.f;
        #pragma unroll
        for (int f = 0; f < 128; f += 4) {
            const float w0 = W[(f + 0) * 64 + lane];
            const float w1 = W[(f + 1) * 64 + lane];
            const float w2 = W[(f + 2) * 64 + lane];
            const float w3 = W[(f + 3) * 64 + lane];
            const float4 v0 = *(const float4*)(ip + f);          // uniform -> s_load
            const float4 v1 = *(const float4*)(ip + 128 + f);
            const float4 v2 = *(const float4*)(ip + 256 + f);
            const float4 v3 = *(const float4*)(ip + 384 + f);
            ac0 += v0.x * w0; ac0 += v0.y * w1; ac0 += v0.z * w2; ac0 += v0.w * w3;
            ac1 += v1.x * w0; ac1 += v1.y * w1; ac1 += v1.z * w2; ac1 += v1.w * w3;
            ac2 += v2.x * w0; ac2 += v2.y * w1; ac2 += v2.z * w2; ac2 += v2.w * w3;
            ac3 += v3.x * w0; ac3 += v3.y * w1; ac3 += v3.z * w2; ac3 += v3.w * w3;
        }
        float acr[4] = {ac0, ac1, ac2, ac3};
        #pragma unroll
        for (int r = 0; r < 4; ++r) {
            hs[rloc + r][lane] = acr[r];
            float r1 = acr[r] * a1;
            float r2 = acr[r] * a2;
            #pragma unroll
            for (int off = 32; off > 0; off >>= 1) {
                r1 += __shfl_xor(r1, off);
                r2 += __shfl_xor(r2, off);
            }
            if (lane == 0) {
                e1[b * 4096 + row + r]  = make_float2(__expf(r1), __expf(LEAKY_ALPHA * r1));
                e2h[b * 4096 + row + r] = __floats2half2_rn(__expf(r2), __expf(LEAKY_ALPHA * r2));
            }
        }
    }
    __syncthreads();

    // write tiled+permuted hT: thread (o = tid&63) writes 8 consecutive nc'
    const int o   = tid & 63;
    const int nco = (tid >> 6) * 8;     // 0,8,16,24
    unsigned pk[4];
    #pragma unroll
    for (int s = 0; s < 8; s += 2) {
        const int n0 = nco + s, n1 = nco + s + 1;
        const int c0 = 4 * (n0 & 7) + (n0 >> 3);    // permuted source col
        const int c1 = 4 * (n1 & 7) + (n1 >> 3);
        unsigned lo = f2bf_rne(hs[c0][o]);   // row uniform/wave: LDS broadcast
        unsigned hi = f2bf_rne(hs[c1][o]);
        pk[s >> 1] = lo | (hi << 16);
    }
    unsigned short* dst = hT + (((size_t)b * 128 + tile) * 64 + o) * 32 + nco;
    *(int4*)(dst) = *(int4*)&pk[0];
}

// ---------------------------------------------------------------------------
// Kernel 2 (FUSED, PRODUCER/CONSUMER ROLE-SPLIT) — verbatim round-2 (passed,
// ~87us, ~97% of its adj-BW floor):
//   waves 2,3 = PRODUCERS: sweep adj for 16 rows each, 1024-col super-groups
//     (4 KB contiguous per row per sg -> page-friendly), ballot -> mask LDS
//     immediately (nothing held across compute). Register-light.
//   waves 0,1 = CONSUMERS: 16 rows each x ALL 128 col-tiles of softmax+PV
//     MFMA from mask LDS + L2-resident hT. One wave owns a full output row
//     block => NO cross-wave accumulator merge, no epilogue LDS, direct out.
// Sync: 4 barriers total; mask slots disjoint per super-group.
// grid 1024 (8 b x 128 row-tiles of 32), block 256 = 4 waves, 4 blocks/CU.
// ---------------------------------------------------------------------------
__global__ __launch_bounds__(256, 4) void k_fused(const int* __restrict__ adj,
                                                  const unsigned short* __restrict__ hT,
                                                  const float2* __restrict__ e1g,
                                                  const __half2* __restrict__ e2hg,
                                                  float* __restrict__ out) {
    __shared__ unsigned long long mask64[32][16][4];   // 16 KB
    __shared__ unsigned e2su[4096];                    // permuted (E2p,E2n) half2, 16 KB

    const int tid   = threadIdx.x;
    const int b     = blockIdx.x >> 7;
    const int rtile = blockIdx.x & 127;
    const int wv    = tid >> 6;
    const int lane  = tid & 63;
    const int m     = lane & 15;
    const int kh    = lane >> 4;          // 0..3 (= ballot word index q = w)
    const int khs   = kh << 3;

    {   // stage e2h for this batch into PERMUTED slots (all waves)
        const unsigned* src = (const unsigned*)(e2hg + b * 4096);
        #pragma unroll
        for (int t = 0; t < 4; ++t) {
            const int c0 = tid * 16 + t * 4;          // 4 consecutive cols, c0%4==0
            const int4 raw = *(const int4*)(src + c0);
            const int base = (c0 & ~31) + ((c0 & 31) >> 2);   // tile*32 + j
            e2su[base +  0] = (unsigned)raw.x;   // w=0
            e2su[base +  8] = (unsigned)raw.y;   // w=1
            e2su[base + 16] = (unsigned)raw.z;   // w=2
            e2su[base + 24] = (unsigned)raw.w;   // w=3
        }
    }

    // ---- producer state (waves 2,3): rows prow0 .. prow0+15 ----
    const int prow0 = (wv >= 2) ? ((wv - 2) * 16) : 0;
    const int* pA = adj + ((size_t)(b * 4096 + rtile * 32 + prow0)) * 4096 + lane * 4;

    // ---- consumer state (waves 0,1): rows (wv&1)*16.., all 128 tiles ----
    const int rl    = (wv & 1) * 16 + m;         // local row for mask read
    const int rbase = rtile * 32 + (wv & 1) * 16;
    const float2 E1 = e1g[b * 4096 + rbase + m];
    const float E1p = E1.x, E1n = E1.y;

    const unsigned short* hbase = hT + (((size_t)b * 128) * 64 + m) * 32 + khs;
    const unsigned short* hrow0 = hbase;
    const unsigned short* hrow1 = hbase + 512;    // +16 o
    const unsigned short* hrow2 = hbase + 1024;   // +32 o
    const unsigned short* hrow3 = hbase + 1536;   // +48 o

    floatx4 acc0 = (floatx4){0.f,0.f,0.f,0.f};
    floatx4 acc1 = (floatx4){0.f,0.f,0.f,0.f};
    floatx4 acc2 = (floatx4){0.f,0.f,0.f,0.f};
    floatx4 acc3 = (floatx4){0.f,0.f,0.f,0.f};
    float lsum = 0.f;

    // depth-2 hT ring: slot0 = tile 0, slot1 = tile 1
    short8 rb0_0, rb1_0, rb2_0, rb3_0, rb0_1, rb1_1, rb2_1, rb3_1;
    rb0_0 = *(const short8*)(hrow0);         rb1_0 = *(const short8*)(hrow1);
    rb2_0 = *(const short8*)(hrow2);         rb3_0 = *(const short8*)(hrow3);
    rb0_1 = *(const short8*)(hrow0 + 2048);  rb1_1 = *(const short8*)(hrow1 + 2048);
    rb2_1 = *(const short8*)(hrow2 + 2048);  rb3_1 = *(const short8*)(hrow3 + 2048);

    // ---- producer ballot-pack macros ----
#define PB1(LR, G, AV)                                                         \
    {                                                                          \
        const unsigned long long b0 = __ballot(AV.x > 0);                      \
        const unsigned long long b1 = __ballot(AV.y > 0);                      \
        const unsigned long long b2 = __ballot(AV.z > 0);                      \
        const unsigned long long b3 = __ballot(AV.w > 0);                      \
        if (lane == 0) {                                                       \
            ulonglong2* d = (ulonglong2*)&mask64[LR][G][0];                    \
            ulonglong2 t0; t0.x = b0; t0.y = b1;                               \
            ulonglong2 t1; t1.x = b2; t1.y = b3;                               \
            d[0] = t0; d[1] = t1;                                              \
        }                                                                      \
    }

    // one super-group = 1024 cols = groups SG*4 .. SG*4+3; per row: 4 KB
    // contiguous (4 x 1KB NT int4 wave-loads), 2-row unroll for queue depth.
#define PRODUCE_SG(SG)                                                         \
    do {                                                                       \
        const int* ps = pA + (SG) * 1024;                                      \
        _Pragma("unroll 2")                                                    \
        for (int r = 0; r < 16; r += 2) {                                      \
            const int* p0 = ps + (size_t)r * 4096;                             \
            const int* p1 = p0 + 4096;                                         \
            const intx4 a0 = __builtin_nontemporal_load((const intx4*)(p0));       \
            const intx4 a1 = __builtin_nontemporal_load((const intx4*)(p0 + 256)); \
            const intx4 a2 = __builtin_nontemporal_load((const intx4*)(p0 + 512)); \
            const intx4 a3 = __builtin_nontemporal_load((const intx4*)(p0 + 768)); \
            const intx4 a4 = __builtin_nontemporal_load((const intx4*)(p1));       \
            const intx4 a5 = __builtin_nontemporal_load((const intx4*)(p1 + 256)); \
            const intx4 a6 = __builtin_nontemporal_load((const intx4*)(p1 + 512)); \
            const intx4 a7 = __builtin_nontemporal_load((const intx4*)(p1 + 768)); \
            PB1(prow0 + r,     (SG) * 4 + 0, a0)                               \
            PB1(prow0 + r,     (SG) * 4 + 1, a1)                               \
            PB1(prow0 + r,     (SG) * 4 + 2, a2)                               \
            PB1(prow0 + r,     (SG) * 4 + 3, a3)                               \
            PB1(prow0 + r + 1, (SG) * 4 + 0, a4)                               \
            PB1(prow0 + r + 1, (SG) * 4 + 1, a5)                               \
            PB1(prow0 + r + 1, (SG) * 4 + 2, a6)                               \
            PB1(prow0 + r + 1, (SG) * 4 + 3, a7)                               \
        }                                                                      \
    } while (0)

    // prologue: producers sweep super-group 0 while consumers sit ready
    if (wv >= 2) PRODUCE_SG(0);
    __syncthreads();

#define GAT_COL(WRD, T)                                                        \
    {                                                                          \
        const float2 ef = h2f2((unsigned)(WRD));                               \
        const float P  = E1p * ef.x;                                           \
        const float Nn = E1n * ef.y;                                           \
        float p = (P > 1.0f) ? P : Nn;                                         \
        p = ((mb >> (T)) & 1u) ? p : 0.0f;                                     \
        psum += p;                                                             \
        pv[T] = p;                                                             \
    }

// consume ring slot SL holding tile JC; mask byte TT of Mcur; prefetch JC+2
#define GAT_STEP(SL, JC, TT)                                                   \
    do {                                                                       \
        const short8 cb0 = rb0_##SL, cb1 = rb1_##SL;                           \
        const short8 cb2 = rb2_##SL, cb3 = rb3_##SL;                           \
        const int poff = (((JC) + 2) & 127) * 2048;    /* wrap: no OOB tail */ \
        rb0_##SL = *(const short8*)(hrow0 + poff);                             \
        rb1_##SL = *(const short8*)(hrow1 + poff);                             \
        rb2_##SL = *(const short8*)(hrow2 + poff);                             \
        rb3_##SL = *(const short8*)(hrow3 + poff);                             \
        const int soff = (JC) * 32 + khs;                                      \
        const int4 eA = *(const int4*)&e2su[soff];                             \
        const int4 eB = *(const int4*)&e2su[soff + 4];                         \
        const unsigned mb = (unsigned)(Mcur >> (8 * (TT))) & 0xffu;            \
        float pv[8];                                                           \
        float psum = 0.f;                                                      \
        GAT_COL(eA.x, 0) GAT_COL(eA.y, 1) GAT_COL(eA.z, 2) GAT_COL(eA.w, 3)    \
        GAT_COL(eB.x, 4) GAT_COL(eB.y, 5) GAT_COL(eB.z, 6) GAT_COL(eB.w, 7)    \
        lsum += psum;                                                          \
        int4 ai;                                                               \
        ai.x = pk2bf(pv[0], pv[1]); ai.y = pk2bf(pv[2], pv[3]);                \
        ai.z = pk2bf(pv[4], pv[5]); ai.w = pk2bf(pv[6], pv[7]);                \
        union { int4 i; short8 s; } cc; cc.i = ai;                             \
        const short8 af = cc.s;                                                \
        acc0 = __builtin_amdgcn_mfma_f32_16x16x32_bf16(af, cb0, acc0, 0,0,0);  \
        acc1 = __builtin_amdgcn_mfma_f32_16x16x32_bf16(af, cb1, acc1, 0,0,0);  \
        acc2 = __builtin_amdgcn_mfma_f32_16x16x32_bf16(af, cb2, acc2, 0,0,0);  \
        acc3 = __builtin_amdgcn_mfma_f32_16x16x32_bf16(af, cb3, acc3, 0,0,0);  \
    } while (0)

    // ---- main loop: producers fill sg+1 while consumers eat sg ----
    #pragma unroll 1
    for (int sg = 0; sg < 4; ++sg) {
        if (wv >= 2) {
            if (sg < 3) PRODUCE_SG(sg + 1);
        } else {
            #pragma unroll
            for (int g4 = 0; g4 < 4; ++g4) {
                const int g = sg * 4 + g4;
                const unsigned long long Mcur =
                    *(const unsigned long long*)&mask64[rl][g][kh];
                const int j0 = g * 8;
                GAT_STEP(0, j0 + 0, 0); GAT_STEP(1, j0 + 1, 1);
                GAT_STEP(0, j0 + 2, 2); GAT_STEP(1, j0 + 3, 3);
                GAT_STEP(0, j0 + 4, 4); GAT_STEP(1, j0 + 5, 5);
                GAT_STEP(0, j0 + 6, 6); GAT_STEP(1, j0 + 7, 7);
            }
        }
        if (sg < 3) __syncthreads();   // masks for sg+1 visible to consumers
    }
#undef GAT_STEP
#undef GAT_COL
#undef PRODUCE_SG
#undef PB1

    // ---- consumer epilogue: no cross-wave merge needed ----
    if (wv < 2) {
        lsum += __shfl_xor(lsum, 16);   // reduce rowsum across the 4 kh-groups
        lsum += __shfl_xor(lsum, 32);
        const float ltot = lsum;
        floatx4 accs[4] = {acc0, acc1, acc2, acc3};
        #pragma unroll
        for (int f = 0; f < 4; ++f) {
            #pragma unroll
            for (int r = 0; r < 4; ++r) {
                const int drow = kh * 4 + r;            // C/D layout row
                const float lr = __shfl(ltot, drow);
                const float v  = accs[f][r];
                const float hp = v / lr;
                const float o  = (hp > 0.f) ? hp : (__expf(hp) - 1.f);  // elu
                out[((size_t)(b * 4096 + rbase + drow)) * 64 + f * 16 + m] = o;
            }
        }
    }
}

// ---------------------------------------------------------------------------
extern "C" void kernel_launch(void* const* d_in, const int* in_sizes, int n_in,
                              void* d_out, int out_size, void* d_ws, size_t ws_size,
                              hipStream_t stream) {
    const float* inp = (const float*)d_in[0];   // (8,4096,128) fp32
    const int*   adj = (const int*)d_in[1];     // (8,4096,4096) int32
    const float* W   = (const float*)d_in[2];   // (128,64) fp32
    const float* a   = (const float*)d_in[3];   // (128,1) fp32
    float* out = (float*)d_out;                 // (8,4096,64) fp32

    unsigned short* hT = (unsigned short*)d_ws;                                // 4 MiB (tiled+perm)
    float2*  e1  = (float2*)((char*)d_ws + (size_t)4 * 1024 * 1024);           // 256 KB
    __half2* e2h = (__half2*)((char*)d_ws + (size_t)4 * 1024 * 1024 + 262144); // 128 KB

    k_h<<<1024, 256, 0, stream>>>(inp, W, a, hT, e1, e2h);
    k_fused<<<1024, 256, 0, stream>>>(adj, hT, e1, e2h, out);
}

// Round 5
// 772.564 us; speedup vs baseline: 1.0268x; 1.0268x over previous
//
#include <hip/hip_runtime.h>
#include <hip/hip_bf16.h>
#include <hip/hip_fp16.h>
#include <cstdint>

typedef __attribute__((ext_vector_type(8))) short short8;   // 8 bf16 = 4 VGPRs
typedef __attribute__((ext_vector_type(4))) float floatx4;  // 4 fp32 acc
typedef __attribute__((ext_vector_type(4))) int   intx4;    // for nontemporal ld

#define LEAKY_ALPHA 0.2f

__device__ __forceinline__ unsigned short f2bf_rne(float f) {
    unsigned u = __float_as_uint(f);
    unsigned r = u + 0x7FFFu + ((u >> 16) & 1u);   // round-to-nearest-even
    return (unsigned short)(r >> 16);
}

__device__ __forceinline__ unsigned pk2bf(float lo, float hi) {   // v_cvt_pk_bf16_f32
    union { __hip_bfloat162 b; unsigned u; } c;
    c.b = __float22bfloat162_rn(make_float2(lo, hi));
    return c.u;
}

__device__ __forceinline__ float2 h2f2(unsigned w) {
    union { unsigned u; __half2 h; } c; c.u = w;
    return __half22float2(c.h);
}

// Within-tile column permutation (shared by k_h hT order, e2s staging, ballot
// mask): storage slot nc' = 8w + j  <->  in-tile column 4j + w  (w=0..3,j=0..7)

// ---------------------------------------------------------------------------
// Kernel 1: h = inp @ W (fp32); e1=(exp(s1),exp(.2*s1)) fp32 per row,
// e2h=(exp(s2),exp(.2*s2)) half2 per col; hT bf16 TILED+PERMUTED:
// [b][tile=n/32][o(64)][nc'] with nc' = 8*(col%4) + col/4 within the tile.
// VERIFIED round-2 form (~15us). Two restructuring attempts regressed:
//  - cooperative fusion into k_fused: coop launch silently no-ops under the
//    harness graph capture (round 3, output never written);
//  - 4-row-blocked inner loop: 4 concurrent wave-uniform s_load streams x
//    full unroll -> scalar-path pressure, k_h ~15 -> ~36us (round 4).
// Single uniform stream + 2 blocks/CU is the measured best. Do not "improve".
// ---------------------------------------------------------------------------
__global__ __launch_bounds__(256) void k_h(const float* __restrict__ inp,
                                           const float* __restrict__ W,
                                           const float* __restrict__ a,
                                           unsigned short* __restrict__ hT,
                                           float2* __restrict__ e1,
                                           __half2* __restrict__ e2h) {
    __shared__ float hs[64][65];   // +1 pad
    const int tid  = threadIdx.x;
    const int wv   = tid >> 6;
    const int lane = tid & 63;
    const int blk  = blockIdx.x;
    const int b     = blk >> 6;         // 0..7
    const int ibase = (blk & 63) * 64;  // row tile base

    const float a1 = a[lane];
    const float a2 = a[64 + lane];

    for (int rr = 0; rr < 16; ++rr) {
        const int rloc = wv * 16 + rr;
        const int row  = ibase + rloc;
        const float* ip = inp + ((size_t)(b * 4096 + row)) * 128;  // wave-uniform
        float acc = 0.f;
        #pragma unroll
        for (int f = 0; f < 128; f += 4) {
            float4 v = *(const float4*)(ip + f);   // uniform -> s_load
            acc += v.x * W[(f + 0) * 64 + lane];
            acc += v.y * W[(f + 1) * 64 + lane];
            acc += v.z * W[(f + 2) * 64 + lane];
            acc += v.w * W[(f + 3) * 64 + lane];
        }
        hs[rloc][lane] = acc;
        float r1 = acc * a1;
        float r2 = acc * a2;
        #pragma unroll
        for (int off = 32; off > 0; off >>= 1) {
            r1 += __shfl_xor(r1, off);
            r2 += __shfl_xor(r2, off);
        }
        if (lane == 0) {
            e1[b * 4096 + row]  = make_float2(__expf(r1), __expf(LEAKY_ALPHA * r1));
            e2h[b * 4096 + row] = __floats2half2_rn(__expf(r2), __expf(LEAKY_ALPHA * r2));
        }
    }
    __syncthreads();

    // write tiled+permuted hT: thread (o, half) writes 16 consecutive nc'
    const int o    = tid & 63;
    const int half = tid >> 6;          // 0..3
    const int tl   = half >> 1;         // local tile 0..1
    const int nco  = (half & 1) * 16;   // nc' offset 0 or 16
    unsigned pk[8];
    #pragma unroll
    for (int s = 0; s < 16; s += 2) {
        const int n0 = nco + s, n1 = nco + s + 1;
        const int c0 = 4 * (n0 & 7) + (n0 >> 3);    // permuted source col
        const int c1 = 4 * (n1 & 7) + (n1 >> 3);
        unsigned lo = f2bf_rne(hs[tl * 32 + c0][o]);   // row uniform/wave: bcast
        unsigned hi = f2bf_rne(hs[tl * 32 + c1][o]);
        pk[s >> 1] = lo | (hi << 16);
    }
    const int tile = (ibase >> 5) + tl;
    unsigned short* dst = hT + (((size_t)b * 128 + tile) * 64 + o) * 32 + nco;
    *(int4*)(dst)     = *(int4*)&pk[0];
    *(int4*)(dst + 8) = *(int4*)&pk[4];
}

// ---------------------------------------------------------------------------
// Kernel 2 (FUSED, PRODUCER/CONSUMER ROLE-SPLIT) — verified round-2 form
// (~87us, ~96-97% of its adj-BW floor of 512 MiB @ ~6.4 TB/s):
//   waves 2,3 = PRODUCERS: sweep adj for 16 rows each, 1024-col super-groups
//     (4 KB contiguous per row per sg -> page-friendly), ballot -> mask LDS
//     immediately (nothing held across compute). Register-light.
//   waves 0,1 = CONSUMERS: 16 rows each x ALL 128 col-tiles of factorized
//     masked softmax + PV MFMA from mask LDS + L2-resident hT. One wave owns
//     a full output row block => NO cross-wave accumulator merge, direct out.
// Sync: 4 barriers total; mask slots disjoint per super-group.
// grid 1024 (8 b x 128 row-tiles of 32), block 256 = 4 waves, 4 blocks/CU.
// ---------------------------------------------------------------------------
__global__ __launch_bounds__(256, 4) void k_fused(const int* __restrict__ adj,
                                                  const unsigned short* __restrict__ hT,
                                                  const float2* __restrict__ e1g,
                                                  const __half2* __restrict__ e2hg,
                                                  float* __restrict__ out) {
    __shared__ unsigned long long mask64[32][16][4];   // 16 KB
    __shared__ unsigned e2su[4096];                    // permuted (E2p,E2n) half2, 16 KB

    const int tid   = threadIdx.x;
    const int b     = blockIdx.x >> 7;
    const int rtile = blockIdx.x & 127;
    const int wv    = tid >> 6;
    const int lane  = tid & 63;
    const int m     = lane & 15;
    const int kh    = lane >> 4;          // 0..3 (= ballot word index q = w)
    const int khs   = kh << 3;

    {   // stage e2h for this batch into PERMUTED slots (all waves)
        const unsigned* src = (const unsigned*)(e2hg + b * 4096);
        #pragma unroll
        for (int t = 0; t < 4; ++t) {
            const int c0 = tid * 16 + t * 4;          // 4 consecutive cols, c0%4==0
            const int4 raw = *(const int4*)(src + c0);
            const int base = (c0 & ~31) + ((c0 & 31) >> 2);   // tile*32 + j
            e2su[base +  0] = (unsigned)raw.x;   // w=0
            e2su[base +  8] = (unsigned)raw.y;   // w=1
            e2su[base + 16] = (unsigned)raw.z;   // w=2
            e2su[base + 24] = (unsigned)raw.w;   // w=3
        }
    }

    // ---- producer state (waves 2,3): rows prow0 .. prow0+15 ----
    const int prow0 = (wv >= 2) ? ((wv - 2) * 16) : 0;
    const int* pA = adj + ((size_t)(b * 4096 + rtile * 32 + prow0)) * 4096 + lane * 4;

    // ---- consumer state (waves 0,1): rows (wv&1)*16.., all 128 tiles ----
    const int rl    = (wv & 1) * 16 + m;         // local row for mask read
    const int rbase = rtile * 32 + (wv & 1) * 16;
    const float2 E1 = e1g[b * 4096 + rbase + m];
    const float E1p = E1.x, E1n = E1.y;

    const unsigned short* hbase = hT + (((size_t)b * 128) * 64 + m) * 32 + khs;
    const unsigned short* hrow0 = hbase;
    const unsigned short* hrow1 = hbase + 512;    // +16 o
    const unsigned short* hrow2 = hbase + 1024;   // +32 o
    const unsigned short* hrow3 = hbase + 1536;   // +48 o

    floatx4 acc0 = (floatx4){0.f,0.f,0.f,0.f};
    floatx4 acc1 = (floatx4){0.f,0.f,0.f,0.f};
    floatx4 acc2 = (floatx4){0.f,0.f,0.f,0.f};
    floatx4 acc3 = (floatx4){0.f,0.f,0.f,0.f};
    float lsum = 0.f;

    // depth-2 hT ring: slot0 = tile 0, slot1 = tile 1
    short8 rb0_0, rb1_0, rb2_0, rb3_0, rb0_1, rb1_1, rb2_1, rb3_1;
    rb0_0 = *(const short8*)(hrow0);         rb1_0 = *(const short8*)(hrow1);
    rb2_0 = *(const short8*)(hrow2);         rb3_0 = *(const short8*)(hrow3);
    rb0_1 = *(const short8*)(hrow0 + 2048);  rb1_1 = *(const short8*)(hrow1 + 2048);
    rb2_1 = *(const short8*)(hrow2 + 2048);  rb3_1 = *(const short8*)(hrow3 + 2048);

    // ---- producer ballot-pack macros ----
#define PB1(LR, G, AV)                                                         \
    {                                                                          \
        const unsigned long long b0 = __ballot(AV.x > 0);                      \
        const unsigned long long b1 = __ballot(AV.y > 0);                      \
        const unsigned long long b2 = __ballot(AV.z > 0);                      \
        const unsigned long long b3 = __ballot(AV.w > 0);                      \
        if (lane == 0) {                                                       \
            ulonglong2* d = (ulonglong2*)&mask64[LR][G][0];                    \
            ulonglong2 t0; t0.x = b0; t0.y = b1;                               \
            ulonglong2 t1; t1.x = b2; t1.y = b3;                               \
            d[0] = t0; d[1] = t1;                                              \
        }                                                                      \
    }

    // one super-group = 1024 cols = groups SG*4 .. SG*4+3; per row: 4 KB
    // contiguous (4 x 1KB NT int4 wave-loads), 2-row unroll for queue depth.
#define PRODUCE_SG(SG)                                                         \
    do {                                                                       \
        const int* ps = pA + (SG) * 1024;                                      \
        _Pragma("unroll 2")                                                    \
        for (int r = 0; r < 16; r += 2) {                                      \
            const int* p0 = ps + (size_t)r * 4096;                             \
            const int* p1 = p0 + 4096;                                         \
            const intx4 a0 = __builtin_nontemporal_load((const intx4*)(p0));       \
            const intx4 a1 = __builtin_nontemporal_load((const intx4*)(p0 + 256)); \
            const intx4 a2 = __builtin_nontemporal_load((const intx4*)(p0 + 512)); \
            const intx4 a3 = __builtin_nontemporal_load((const intx4*)(p0 + 768)); \
            const intx4 a4 = __builtin_nontemporal_load((const intx4*)(p1));       \
            const intx4 a5 = __builtin_nontemporal_load((const intx4*)(p1 + 256)); \
            const intx4 a6 = __builtin_nontemporal_load((const intx4*)(p1 + 512)); \
            const intx4 a7 = __builtin_nontemporal_load((const intx4*)(p1 + 768)); \
            PB1(prow0 + r,     (SG) * 4 + 0, a0)                               \
            PB1(prow0 + r,     (SG) * 4 + 1, a1)                               \
            PB1(prow0 + r,     (SG) * 4 + 2, a2)                               \
            PB1(prow0 + r,     (SG) * 4 + 3, a3)                               \
            PB1(prow0 + r + 1, (SG) * 4 + 0, a4)                               \
            PB1(prow0 + r + 1, (SG) * 4 + 1, a5)                               \
            PB1(prow0 + r + 1, (SG) * 4 + 2, a6)                               \
            PB1(prow0 + r + 1, (SG) * 4 + 3, a7)                               \
        }                                                                      \
    } while (0)

    // prologue: producers sweep super-group 0 while consumers sit ready
    if (wv >= 2) PRODUCE_SG(0);
    __syncthreads();

#define GAT_COL(WRD, T)                                                        \
    {                                                                          \
        const float2 ef = h2f2((unsigned)(WRD));                               \
        const float P  = E1p * ef.x;                                           \
        const float Nn = E1n * ef.y;                                           \
        float p = (P > 1.0f) ? P : Nn;                                         \
        p = ((mb >> (T)) & 1u) ? p : 0.0f;                                     \
        psum += p;                                                             \
        pv[T] = p;                                                             \
    }

// consume ring slot SL holding tile JC; mask byte TT of Mcur; prefetch JC+2
#define GAT_STEP(SL, JC, TT)                                                   \
    do {                                                                       \
        const short8 cb0 = rb0_##SL, cb1 = rb1_##SL;                           \
        const short8 cb2 = rb2_##SL, cb3 = rb3_##SL;                           \
        const int poff = (((JC) + 2) & 127) * 2048;    /* wrap: no OOB tail */ \
        rb0_##SL = *(const short8*)(hrow0 + poff);                             \
        rb1_##SL = *(const short8*)(hrow1 + poff);                             \
        rb2_##SL = *(const short8*)(hrow2 + poff);                             \
        rb3_##SL = *(const short8*)(hrow3 + poff);                             \
        const int soff = (JC) * 32 + khs;                                      \
        const int4 eA = *(const int4*)&e2su[soff];                             \
        const int4 eB = *(const int4*)&e2su[soff + 4];                         \
        const unsigned mb = (unsigned)(Mcur >> (8 * (TT))) & 0xffu;            \
        float pv[8];                                                           \
        float psum = 0.f;                                                      \
        GAT_COL(eA.x, 0) GAT_COL(eA.y, 1) GAT_COL(eA.z, 2) GAT_COL(eA.w, 3)    \
        GAT_COL(eB.x, 4) GAT_COL(eB.y, 5) GAT_COL(eB.z, 6) GAT_COL(eB.w, 7)    \
        lsum += psum;                                                          \
        int4 ai;                                                               \
        ai.x = pk2bf(pv[0], pv[1]); ai.y = pk2bf(pv[2], pv[3]);                \
        ai.z = pk2bf(pv[4], pv[5]); ai.w = pk2bf(pv[6], pv[7]);                \
        union { int4 i; short8 s; } cc; cc.i = ai;                             \
        const short8 af = cc.s;                                                \
        acc0 = __builtin_amdgcn_mfma_f32_16x16x32_bf16(af, cb0, acc0, 0,0,0);  \
        acc1 = __builtin_amdgcn_mfma_f32_16x16x32_bf16(af, cb1, acc1, 0,0,0);  \
        acc2 = __builtin_amdgcn_mfma_f32_16x16x32_bf16(af, cb2, acc2, 0,0,0);  \
        acc3 = __builtin_amdgcn_mfma_f32_16x16x32_bf16(af, cb3, acc3, 0,0,0);  \
    } while (0)

    // ---- main loop: producers fill sg+1 while consumers eat sg ----
    #pragma unroll 1
    for (int sg = 0; sg < 4; ++sg) {
        if (wv >= 2) {
            if (sg < 3) PRODUCE_SG(sg + 1);
        } else {
            #pragma unroll
            for (int g4 = 0; g4 < 4; ++g4) {
                const int g = sg * 4 + g4;
                const unsigned long long Mcur =
                    *(const unsigned long long*)&mask64[rl][g][kh];
                const int j0 = g * 8;
                GAT_STEP(0, j0 + 0, 0); GAT_STEP(1, j0 + 1, 1);
                GAT_STEP(0, j0 + 2, 2); GAT_STEP(1, j0 + 3, 3);
                GAT_STEP(0, j0 + 4, 4); GAT_STEP(1, j0 + 5, 5);
                GAT_STEP(0, j0 + 6, 6); GAT_STEP(1, j0 + 7, 7);
            }
        }
        if (sg < 3) __syncthreads();   // masks for sg+1 visible to consumers
    }
#undef GAT_STEP
#undef GAT_COL
#undef PRODUCE_SG
#undef PB1

    // ---- consumer epilogue: no cross-wave merge needed ----
    if (wv < 2) {
        lsum += __shfl_xor(lsum, 16);   // reduce rowsum across the 4 kh-groups
        lsum += __shfl_xor(lsum, 32);
        const float ltot = lsum;
        floatx4 accs[4] = {acc0, acc1, acc2, acc3};
        #pragma unroll
        for (int f = 0; f < 4; ++f) {
            #pragma unroll
            for (int r = 0; r < 4; ++r) {
                const int drow = kh * 4 + r;            // C/D layout row
                const float lr = __shfl(ltot, drow);
                const float v  = accs[f][r];
                const float hp = v / lr;
                const float o  = (hp > 0.f) ? hp : (__expf(hp) - 1.f);  // elu
                out[((size_t)(b * 4096 + rbase + drow)) * 64 + f * 16 + m] = o;
            }
        }
    }
}

// ---------------------------------------------------------------------------
extern "C" void kernel_launch(void* const* d_in, const int* in_sizes, int n_in,
                              void* d_out, int out_size, void* d_ws, size_t ws_size,
                              hipStream_t stream) {
    const float* inp = (const float*)d_in[0];   // (8,4096,128) fp32
    const int*   adj = (const int*)d_in[1];     // (8,4096,4096) int32
    const float* W   = (const float*)d_in[2];   // (128,64) fp32
    const float* a   = (const float*)d_in[3];   // (128,1) fp32
    float* out = (float*)d_out;                 // (8,4096,64) fp32

    unsigned short* hT = (unsigned short*)d_ws;                                // 4 MiB (tiled+perm)
    float2*  e1  = (float2*)((char*)d_ws + (size_t)4 * 1024 * 1024);           // 256 KB
    __half2* e2h = (__half2*)((char*)d_ws + (size_t)4 * 1024 * 1024 + 262144); // 128 KB

    k_h<<<512, 256, 0, stream>>>(inp, W, a, hT, e1, e2h);
    k_fused<<<1024, 256, 0, stream>>>(adj, hT, e1, e2h, out);
}